// Round 4
// baseline (328.196 us; speedup 1.0000x reference)
//
#include <hip/hip_runtime.h>
#include <math.h>

#define DD 128
#define NEG 0.01f

typedef __attribute__((ext_vector_type(8))) _Float16 half8;
typedef __attribute__((ext_vector_type(4))) float f32x4;

__device__ __forceinline__ float lrelu(float x){ return x > 0.f ? x : NEG * x; }

__device__ __forceinline__ unsigned short h2u(_Float16 h){
    union { _Float16 h; unsigned short u; } v; v.h = h; return v.u;
}
__device__ __forceinline__ _Float16 u2h(unsigned short u){
    union { unsigned short u; _Float16 h; } v; v.u = u; return v.h;
}

__device__ __forceinline__ half8 h8max(half8 x, half8 y){
#if __has_builtin(__builtin_elementwise_max)
    return __builtin_elementwise_max(x, y);
#else
    half8 r;
    #pragma unroll
    for (int i = 0; i < 8; i++) r[i] = x[i] > y[i] ? x[i] : y[i];
    return r;
#endif
}

// histogram + fp16 weight pack fused (disjoint block ranges)
// wpack segs: 0 Wa1, 1 Wsrc, 2 Wdst, 3 Wout — MFMA B-fragment-linear order
__global__ void hist_pack(const int* dst, int* deg, int E, int nhist,
                          const float* Wa1, const float* Wsrc,
                          const float* Wdst, const float* Wout,
                          unsigned short* wpack){
    const int bid = blockIdx.x;
    if (bid < nhist){
        int i = bid * 256 + threadIdx.x;
        if (i < E) atomicAdd(&deg[dst[i]], 1);
    } else {
        int i = (bid - nhist) * 256 + threadIdx.x;   // [0, 4*16384)
        if (i >= 4 * 16384) return;
        int seg = i >> 14, t = i & 16383;
        int j = t & 7, lane = (t >> 3) & 63, nt = (t >> 9) & 7, kc = t >> 12;
        int k = kc * 32 + (lane >> 4) * 8 + j;
        int n = nt * 16 + (lane & 15);
        const float* W = (seg == 0) ? Wa1 : (seg == 1) ? Wsrc : (seg == 2) ? Wdst : Wout;
        wpack[i] = h2u((_Float16)W[k * DD + n]);
    }
}

// single-block exclusive scan over deg[0..n) -> row_off, cursor; row_off[n]=total
__global__ __launch_bounds__(1024) void scan_all(const int* deg, int* row_off,
                                                 int* cursor, int n){
    __shared__ int wsum[16];
    const int tid = threadIdx.x;
    const int lane = tid & 63, wid = tid >> 6;
    const int per = ((n + 4095) >> 12) << 2;     // ints per thread, multiple of 4
    const int base = tid * per;
    int s = 0;
    for (int i = 0; i < per; i += 4){
        int idx = base + i;
        if (idx + 3 < n){
            int4 v = *(const int4*)(deg + idx);
            s += v.x + v.y + v.z + v.w;
        } else {
            #pragma unroll
            for (int k = 0; k < 4; k++) if (idx + k < n) s += deg[idx + k];
        }
    }
    int x = s;
    #pragma unroll
    for (int off = 1; off < 64; off <<= 1){
        int t = __shfl_up(x, off, 64);
        if (lane >= off) x += t;
    }
    if (lane == 63) wsum[wid] = x;
    __syncthreads();
    int wpre = 0;
    #pragma unroll
    for (int j = 0; j < 16; j++) if (j < wid) wpre += wsum[j];
    int a = wpre + (x - s);   // exclusive prefix for this thread's range
    for (int i = 0; i < per; i += 4){
        int idx = base + i;
        if (idx + 3 < n){
            int4 v = *(const int4*)(deg + idx);
            int4 o; o.x = a; o.y = a + v.x; o.z = o.y + v.y; o.w = o.z + v.z;
            *(int4*)(row_off + idx) = o;
            *(int4*)(cursor + idx) = o;
            a = o.w + v.w;
        } else {
            #pragma unroll
            for (int k = 0; k < 4; k++) if (idx + k < n){
                row_off[idx + k] = a; cursor[idx + k] = a; a += deg[idx + k];
            }
        }
    }
    if (tid == 0){
        int tot = 0;
        #pragma unroll
        for (int j = 0; j < 16; j++) tot += wsum[j];
        row_off[n] = tot;
    }
}

// bucket edges by dst: sorted (src,dst) pairs in CSR order
__global__ void scatter_pairs(const int* src, const int* dst, int* cursor,
                              int2* pairs, int E){
    int i = blockIdx.x * blockDim.x + threadIdx.x;
    if (i < E){
        int d = dst[i];
        int s = src[i];
        int pos = atomicAdd(&cursor[d], 1);
        pairs[pos] = make_int2(s, d);
    }
}

// Node linear via single fp16 MFMA (~1e-3 abs accuracy, sufficient).
// Y[r] = X[r] @ W + b (fp16 out). 128 rows/block (4 waves x 32 rows).
// Fused: blocks [0,g1): (X1,W1,b1)->Yb1; blocks [g1,..): (X2,W2,b2)->Yb2.
__global__ __launch_bounds__(256) void lin2_mfma(
        const float* X1, const unsigned short* W1, const float* b1,
        unsigned short* Yb1, int n1, int g1,
        const float* X2, const unsigned short* W2, const float* b2,
        unsigned short* Yb2, int n2){
    __shared__ unsigned short sB[16384];   // 32 KB
    const int tid = threadIdx.x;
    const int second = (blockIdx.x >= g1);
    const float* X = second ? X2 : X1;
    const unsigned short* W = second ? W2 : W1;
    const float* b = second ? b2 : b1;
    unsigned short* Yb = second ? Yb2 : Yb1;
    const int nrows = second ? n2 : n1;
    const int bidx = second ? (blockIdx.x - g1) : blockIdx.x;
    {
        const uint4* g = (const uint4*)W;
        uint4* l = (uint4*)sB;
        #pragma unroll
        for (int t = 0; t < 8; t++) l[tid + 256 * t] = g[tid + 256 * t];
    }
    const int wave = tid >> 6, lane = tid & 63;
    const int qd = lane >> 4, ln16 = lane & 15;
    const int row0 = bidx * 128 + wave * 32;
    int r0 = row0 + ln16;       if (r0 >= nrows) r0 = nrows - 1;
    int r1 = row0 + 16 + ln16;  if (r1 >= nrows) r1 = nrows - 1;
    f32x4 acc[2][8];
    #pragma unroll
    for (int rt = 0; rt < 2; rt++)
        #pragma unroll
        for (int nt = 0; nt < 8; nt++)
            acc[rt][nt] = (f32x4){0.f, 0.f, 0.f, 0.f};
    __syncthreads();
    #pragma unroll
    for (int kc = 0; kc < 4; kc++){
        const int koff = kc * 32 + qd * 8;
        half8 a[2];
        const float* px[2] = {X + (size_t)r0 * DD + koff, X + (size_t)r1 * DD + koff};
        #pragma unroll
        for (int rt = 0; rt < 2; rt++){
            float4 v0 = *(const float4*)(px[rt]);
            float4 v1 = *(const float4*)(px[rt] + 4);
            a[rt][0] = (_Float16)v0.x; a[rt][1] = (_Float16)v0.y;
            a[rt][2] = (_Float16)v0.z; a[rt][3] = (_Float16)v0.w;
            a[rt][4] = (_Float16)v1.x; a[rt][5] = (_Float16)v1.y;
            a[rt][6] = (_Float16)v1.z; a[rt][7] = (_Float16)v1.w;
        }
        #pragma unroll
        for (int nt = 0; nt < 8; nt++){
            const int fi = (((kc << 3) + nt) << 6 | lane) << 3;
            half8 bw = *(const half8*)&sB[fi];
            acc[0][nt] = __builtin_amdgcn_mfma_f32_16x16x32_f16(a[0], bw, acc[0][nt], 0, 0, 0);
            acc[1][nt] = __builtin_amdgcn_mfma_f32_16x16x32_f16(a[1], bw, acc[1][nt], 0, 0, 0);
        }
    }
    #pragma unroll
    for (int nt = 0; nt < 8; nt++){
        const int col = nt * 16 + ln16;
        const float bv = b[col];
        #pragma unroll
        for (int rt = 0; rt < 2; rt++){
            #pragma unroll
            for (int r = 0; r < 4; r++){
                int row = row0 + rt * 16 + qd * 4 + r;
                if (row < nrows){
                    float y = acc[rt][nt][r] + bv;
                    Yb[(size_t)row * DD + col] = h2u((_Float16)y);
                }
            }
        }
    }
}

// Final linear (fp32 in/out, in-place): Y = lrelu(X @ W + b)
__global__ __launch_bounds__(256) void lin_mfma(const float* X,
        const unsigned short* W, const float* b, float* Y, int nrows){
    __shared__ unsigned short sB[16384];
    const int tid = threadIdx.x;
    {
        const uint4* g = (const uint4*)W;
        uint4* l = (uint4*)sB;
        #pragma unroll
        for (int t = 0; t < 8; t++) l[tid + 256 * t] = g[tid + 256 * t];
    }
    const int wave = tid >> 6, lane = tid & 63;
    const int qd = lane >> 4, ln16 = lane & 15;
    const int row0 = blockIdx.x * 128 + wave * 32;
    int r0 = row0 + ln16;       if (r0 >= nrows) r0 = nrows - 1;
    int r1 = row0 + 16 + ln16;  if (r1 >= nrows) r1 = nrows - 1;
    f32x4 acc[2][8];
    #pragma unroll
    for (int rt = 0; rt < 2; rt++)
        #pragma unroll
        for (int nt = 0; nt < 8; nt++)
            acc[rt][nt] = (f32x4){0.f, 0.f, 0.f, 0.f};
    __syncthreads();
    #pragma unroll
    for (int kc = 0; kc < 4; kc++){
        const int koff = kc * 32 + qd * 8;
        half8 a[2];
        const float* px[2] = {X + (size_t)r0 * DD + koff, X + (size_t)r1 * DD + koff};
        #pragma unroll
        for (int rt = 0; rt < 2; rt++){
            float4 v0 = *(const float4*)(px[rt]);
            float4 v1 = *(const float4*)(px[rt] + 4);
            a[rt][0] = (_Float16)v0.x; a[rt][1] = (_Float16)v0.y;
            a[rt][2] = (_Float16)v0.z; a[rt][3] = (_Float16)v0.w;
            a[rt][4] = (_Float16)v1.x; a[rt][5] = (_Float16)v1.y;
            a[rt][6] = (_Float16)v1.z; a[rt][7] = (_Float16)v1.w;
        }
        #pragma unroll
        for (int nt = 0; nt < 8; nt++){
            const int fi = (((kc << 3) + nt) << 6 | lane) << 3;
            half8 bw = *(const half8*)&sB[fi];
            acc[0][nt] = __builtin_amdgcn_mfma_f32_16x16x32_f16(a[0], bw, acc[0][nt], 0, 0, 0);
            acc[1][nt] = __builtin_amdgcn_mfma_f32_16x16x32_f16(a[1], bw, acc[1][nt], 0, 0, 0);
        }
    }
    #pragma unroll
    for (int nt = 0; nt < 8; nt++){
        const int col = nt * 16 + ln16;
        const float bv = b[col];
        #pragma unroll
        for (int rt = 0; rt < 2; rt++){
            #pragma unroll
            for (int r = 0; r < 4; r++){
                int row = row0 + rt * 16 + qd * 4 + r;
                if (row < nrows){
                    float y = acc[rt][nt][r] + bv;
                    Y[(size_t)row * DD + col] = lrelu(y);
                }
            }
        }
    }
}

// A-fragment: 8 fp16 of lrelu(hs_row + hd_row) — packed fp16 math.
// lrelu(x) == max(x, 0.01*x), maps to v_pk_max_f16.
__device__ __forceinline__ half8 afrag_from(half8 a, half8 b){
    half8 s = a + b;
    return h8max(s, s * (_Float16)NEG);
}

// MFMA edge attention score on SORTED edges; 256 edges/block (8 waves).
// Round-1 structure (best measured): rt-serialized, b_a1 folded into acc
// init, lrelu via v_max, __expf. exp() without +b2: per-node constant e^b2
// cancels exactly in alpha = ex/sum(ex).
__global__ __launch_bounds__(512) void edge_score_mfma(
        const unsigned short* hs_h, const unsigned short* hd_h,
        const int2* pairs,
        const unsigned short* wa1p, const float* ba1,
        const float* Wa2, const float* ba2,
        float* s_w, int E){
    __shared__ unsigned short sB[16384];  // 32 KB
    const int tid = threadIdx.x;
    {
        const uint4* g = (const uint4*)wa1p;
        uint4* l = (uint4*)sB;
        #pragma unroll
        for (int t = 0; t < 4; t++) l[tid + 512 * t] = g[tid + 512 * t];
    }
    const int wave = tid >> 6, lane = tid & 63;
    const int qd = lane >> 4, ln16 = lane & 15;
    const int e0 = blockIdx.x * 256 + wave * 32;
    float b1v[8], w2v[8];
    #pragma unroll
    for (int nt = 0; nt < 8; nt++){
        b1v[nt] = ba1[nt * 16 + ln16];
        w2v[nt] = Wa2[nt * 16 + ln16];
    }
    __syncthreads();
    for (int rt = 0; rt < 2; rt++){
        int eid = e0 + rt * 16 + ln16;
        if (eid >= E) eid = E - 1;
        const int2 pp = pairs[eid];
        f32x4 acc[8];
        #pragma unroll
        for (int nt = 0; nt < 8; nt++)
            acc[nt] = (f32x4){b1v[nt], b1v[nt], b1v[nt], b1v[nt]};
        #pragma unroll
        for (int kc = 0; kc < 4; kc++){
            const int koff = kc * 32 + qd * 8;
            half8 af = afrag_from(*(const half8*)(hs_h + (size_t)pp.x * DD + koff),
                                  *(const half8*)(hd_h + (size_t)pp.y * DD + koff));
            #pragma unroll
            for (int nt = 0; nt < 8; nt++){
                half8 bf = *(const half8*)&sB[(((kc << 3) + nt) << 6 | lane) << 3];
                acc[nt] = __builtin_amdgcn_mfma_f32_16x16x32_f16(af, bf, acc[nt], 0, 0, 0);
            }
        }
        float p[4] = {0.f, 0.f, 0.f, 0.f};
        #pragma unroll
        for (int nt = 0; nt < 8; nt++)
            #pragma unroll
            for (int r = 0; r < 4; r++){
                float z = acc[nt][r];
                z = fmaxf(z, NEG * z);      // lrelu via v_max_f32
                p[r] += z * w2v[nt];
            }
        #pragma unroll
        for (int r = 0; r < 4; r++){
            float v = p[r];
            #pragma unroll
            for (int off = 1; off < 16; off <<= 1) v += __shfl_xor(v, off, 64);
            p[r] = __expf(v);
        }
        if (ln16 == 0){
            int row = e0 + rt * 16 + qd * 4;
            #pragma unroll
            for (int r = 0; r < 4; r++)
                if (row + r < E) s_w[row + r] = p[r];
        }
    }
}

// one wave per dst node, 4 edges per sub-pass (16-lane groups), 16 edges/iter.
// Lane loads half8 (16 B) — 16 lanes cover a 256 B row; 4 independent gathers
// in flight per pass. Cross-group combine: shfl_xor 16 + 32.
// nf[n] = (sum_e w_e * hs[src_e]) / (sum_e w_e) + hd[n]
__global__ __launch_bounds__(256) void agg_softmax(const unsigned short* hs_h,
        const unsigned short* hd_h, const int* row_off, const int2* pairs,
        const float* s_w, float* nf, int n_dst){
    const int w = (blockIdx.x * blockDim.x + threadIdx.x) >> 6;
    const int lane = threadIdx.x & 63;
    if (w >= n_dst) return;
    const int beg = row_off[w], end = row_off[w + 1];
    const int g = lane >> 4, l16 = lane & 15;
    float va[8] = {0.f, 0.f, 0.f, 0.f, 0.f, 0.f, 0.f, 0.f};
    float sa = 0.f;
    int e = beg;
    for (; e + 15 < end; e += 16){
        int rows[4]; float wv[4]; half8 uv[4];
        #pragma unroll
        for (int j = 0; j < 4; j++){
            int ee = e + 4 * j + g;
            rows[j] = pairs[ee].x;
            wv[j] = s_w[ee];
        }
        #pragma unroll
        for (int j = 0; j < 4; j++)
            uv[j] = *(const half8*)(hs_h + (size_t)rows[j] * DD + l16 * 8);
        #pragma unroll
        for (int j = 0; j < 4; j++){
            #pragma unroll
            for (int k = 0; k < 8; k++)
                va[k] += wv[j] * (float)uv[j][k];
            sa += wv[j];
        }
    }
    for (; e < end; e += 4){
        int ee = e + g;
        float wv = 0.f;
        int row = pairs[beg].x;
        if (ee < end){ row = pairs[ee].x; wv = s_w[ee]; }
        half8 uv = *(const half8*)(hs_h + (size_t)row * DD + l16 * 8);
        #pragma unroll
        for (int k = 0; k < 8; k++)
            va[k] += wv * (float)uv[k];
        sa += wv;
    }
    // combine the four 16-lane-group partials (same dims, disjoint edges)
    #pragma unroll
    for (int k = 0; k < 8; k++){
        va[k] += __shfl_xor(va[k], 16, 64);
        va[k] += __shfl_xor(va[k], 32, 64);
    }
    sa += __shfl_xor(sa, 16, 64);
    sa += __shfl_xor(sa, 32, 64);
    const float inv = (end > beg) ? 1.f / sa : 0.f;
    if (g == 0){
        half8 hu = *(const half8*)(hd_h + (size_t)w * DD + l16 * 8);
        const float gx = (end > beg) ? 1.f : 0.f;
        float4 o0, o1;
        o0.x = va[0] * inv + gx * (float)hu[0];
        o0.y = va[1] * inv + gx * (float)hu[1];
        o0.z = va[2] * inv + gx * (float)hu[2];
        o0.w = va[3] * inv + gx * (float)hu[3];
        o1.x = va[4] * inv + gx * (float)hu[4];
        o1.y = va[5] * inv + gx * (float)hu[5];
        o1.z = va[6] * inv + gx * (float)hu[6];
        o1.w = va[7] * inv + gx * (float)hu[7];
        *(float4*)(nf + (size_t)w * DD + l16 * 8) = o0;
        *(float4*)(nf + (size_t)w * DD + l16 * 8 + 4) = o1;
    }
}

extern "C" void kernel_launch(void* const* d_in, const int* in_sizes, int n_in,
                              void* d_out, int out_size, void* d_ws, size_t ws_size,
                              hipStream_t stream){
    const float* feat_src = (const float*)d_in[0];
    const float* feat_dst = (const float*)d_in[1];
    const int*   src_idx  = (const int*)d_in[2];
    const int*   dst_idx  = (const int*)d_in[3];
    const float* W_src = (const float*)d_in[4];
    const float* b_src = (const float*)d_in[5];
    const float* W_dst = (const float*)d_in[6];
    const float* b_dst = (const float*)d_in[7];
    const float* W_a1  = (const float*)d_in[8];
    const float* b_a1  = (const float*)d_in[9];
    const float* W_a2  = (const float*)d_in[10];
    const float* b_a2  = (const float*)d_in[11];
    const float* W_out = (const float*)d_in[12];
    const float* b_out = (const float*)d_in[13];
    const int n_src = in_sizes[0] / DD;
    const int n_dst = in_sizes[1] / DD;
    const int E = in_sizes[2];

    // workspace layout (all 16B-aligned segments)
    char* p = (char*)d_ws;
    unsigned short* hs_h = (unsigned short*)p;  p += (size_t)n_src * DD * 2;
    unsigned short* hd_h = (unsigned short*)p;  p += (size_t)n_dst * DD * 2;
    unsigned short* wpack = (unsigned short*)p; p += 4 * 16384 * 2;
    float* s_w = (float*)p;                     p += (size_t)E * 4;
    int2* pairs = (int2*)p;                     p += (size_t)E * 8;
    int* deg = (int*)p;                         p += (size_t)n_dst * 4;
    int* cursor = (int*)p;                      p += (size_t)n_dst * 4;
    int* row_off = (int*)p;                     p += ((size_t)n_dst + 1) * 4;
    float* nf = (float*)d_out;

    const unsigned short* wa1p = wpack;
    const unsigned short* wsrc = wpack + 1 * 16384;
    const unsigned short* wdst = wpack + 2 * 16384;
    const unsigned short* wout = wpack + 3 * 16384;

    hipMemsetAsync(deg, 0, (size_t)n_dst * 4, stream);
    const int nhist = (E + 255) / 256;
    const int npack = (4 * 16384 + 255) / 256;
    hist_pack<<<nhist + npack, 256, 0, stream>>>(dst_idx, deg, E, nhist,
                                                 W_a1, W_src, W_dst, W_out, wpack);
    scan_all<<<1, 1024, 0, stream>>>(deg, row_off, cursor, n_dst);
    scatter_pairs<<<(E + 255) / 256, 256, 0, stream>>>(src_idx, dst_idx, cursor,
                                                       pairs, E);
    const int g1 = (n_src + 127) / 128;
    const int g2 = (n_dst + 127) / 128;
    lin2_mfma<<<g1 + g2, 256, 0, stream>>>(feat_src, wsrc, b_src, hs_h, n_src, g1,
                                           feat_dst, wdst, b_dst, hd_h, n_dst);
    edge_score_mfma<<<(E + 255) / 256, 512, 0, stream>>>(hs_h, hd_h, pairs, wa1p, b_a1,
                                                         W_a2, b_a2, s_w, E);
    agg_softmax<<<((size_t)n_dst * 64 + 255) / 256, 256, 0, stream>>>(hs_h, hd_h, row_off,
                                                                      pairs, s_w, nf, n_dst);
    lin_mfma<<<g2, 256, 0, stream>>>(nf, wout, b_out, nf, n_dst);
}

// Round 5
// 293.791 us; speedup vs baseline: 1.1171x; 1.1171x over previous
//
#include <hip/hip_runtime.h>
#include <math.h>

#define DD 128
#define NEG 0.01f
#define SCHUNK 4096

typedef __attribute__((ext_vector_type(8))) _Float16 half8;
typedef __attribute__((ext_vector_type(4))) float f32x4;

__device__ __forceinline__ float lrelu(float x){ return x > 0.f ? x : NEG * x; }

__device__ __forceinline__ unsigned short h2u(_Float16 h){
    union { _Float16 h; unsigned short u; } v; v.h = h; return v.u;
}
__device__ __forceinline__ _Float16 u2h(unsigned short u){
    union { unsigned short u; _Float16 h; } v; v.u = u; return v.h;
}

__device__ __forceinline__ half8 h8max(half8 x, half8 y){
#if __has_builtin(__builtin_elementwise_max)
    return __builtin_elementwise_max(x, y);
#else
    half8 r;
    #pragma unroll
    for (int i = 0; i < 8; i++) r[i] = x[i] > y[i] ? x[i] : y[i];
    return r;
#endif
}

// histogram + fp16 weight pack fused (disjoint block ranges)
// wpack segs: 0 Wa1, 1 Wsrc, 2 Wdst, 3 Wout — MFMA B-fragment-linear order
__global__ void hist_pack(const int* dst, int* deg, int E, int nhist,
                          const float* Wa1, const float* Wsrc,
                          const float* Wdst, const float* Wout,
                          unsigned short* wpack){
    const int bid = blockIdx.x;
    if (bid < nhist){
        int i = bid * 256 + threadIdx.x;
        if (i < E) atomicAdd(&deg[dst[i]], 1);
    } else {
        int i = (bid - nhist) * 256 + threadIdx.x;   // [0, 4*16384)
        if (i >= 4 * 16384) return;
        int seg = i >> 14, t = i & 16383;
        int j = t & 7, lane = (t >> 3) & 63, nt = (t >> 9) & 7, kc = t >> 12;
        int k = kc * 32 + (lane >> 4) * 8 + j;
        int n = nt * 16 + (lane & 15);
        const float* W = (seg == 0) ? Wa1 : (seg == 1) ? Wsrc : (seg == 2) ? Wdst : Wout;
        wpack[i] = h2u((_Float16)W[k * DD + n]);
    }
}

// two-level scan, level 1: per-chunk sums (chunk = 4096 ints)
__global__ __launch_bounds__(1024) void scan1(const int* deg, int* part, int n){
    __shared__ int wsum[16];
    const int tid = threadIdx.x;
    const int lane = tid & 63, wid = tid >> 6;
    int i4 = blockIdx.x * SCHUNK + tid * 4;
    int4 v = make_int4(0, 0, 0, 0);
    if (i4 + 3 < n) v = *(const int4*)(deg + i4);
    else {
        if (i4 + 0 < n) v.x = deg[i4 + 0];
        if (i4 + 1 < n) v.y = deg[i4 + 1];
        if (i4 + 2 < n) v.z = deg[i4 + 2];
        if (i4 + 3 < n) v.w = deg[i4 + 3];
    }
    int t = v.x + v.y + v.z + v.w;
    #pragma unroll
    for (int off = 1; off < 64; off <<= 1) t += __shfl_xor(t, off, 64);
    if (lane == 0) wsum[wid] = t;
    __syncthreads();
    if (tid == 0){
        int s = 0;
        #pragma unroll
        for (int j = 0; j < 16; j++) s += wsum[j];
        part[blockIdx.x] = s;
    }
}

// two-level scan, level 2: exclusive offsets + cursor copy
__global__ __launch_bounds__(1024) void scan2(const int* deg, const int* part,
        int* row_off, int* cursor, int n, int nchunks){
    __shared__ int wsum[16];
    const int tid = threadIdx.x;
    const int lane = tid & 63, wid = tid >> 6;
    const int b = blockIdx.x;
    int carry = 0;
    for (int j = 0; j < b; j++) carry += part[j];
    int i4 = b * SCHUNK + tid * 4;
    int4 v = make_int4(0, 0, 0, 0);
    if (i4 + 3 < n) v = *(const int4*)(deg + i4);
    else {
        if (i4 + 0 < n) v.x = deg[i4 + 0];
        if (i4 + 1 < n) v.y = deg[i4 + 1];
        if (i4 + 2 < n) v.z = deg[i4 + 2];
        if (i4 + 3 < n) v.w = deg[i4 + 3];
    }
    int tsum = v.x + v.y + v.z + v.w;
    int x = tsum;
    #pragma unroll
    for (int off = 1; off < 64; off <<= 1){
        int t = __shfl_up(x, off, 64);
        if (lane >= off) x += t;
    }
    if (lane == 63) wsum[wid] = x;
    __syncthreads();
    int wprefix = 0;
    #pragma unroll
    for (int j = 0; j < 16; j++) if (j < wid) wprefix += wsum[j];
    int excl = carry + wprefix + (x - tsum);
    if (i4 + 3 < n){
        int4 o;
        o.x = excl; o.y = excl + v.x; o.z = o.y + v.y; o.w = o.z + v.z;
        *(int4*)(row_off + i4) = o;
        *(int4*)(cursor + i4) = o;
    } else {
        int a = excl;
        if (i4 + 0 < n){ row_off[i4 + 0] = a; cursor[i4 + 0] = a; a += v.x; }
        if (i4 + 1 < n){ row_off[i4 + 1] = a; cursor[i4 + 1] = a; a += v.y; }
        if (i4 + 2 < n){ row_off[i4 + 2] = a; cursor[i4 + 2] = a; a += v.z; }
        if (i4 + 3 < n){ row_off[i4 + 3] = a; cursor[i4 + 3] = a; }
    }
    if (b == 0 && tid == 0){
        int tot = 0;
        for (int j = 0; j < nchunks; j++) tot += part[j];
        row_off[n] = tot;
    }
}

// bucket edges by dst: sorted (src,dst) pairs in CSR order
__global__ void scatter_pairs(const int* src, const int* dst, int* cursor,
                              int2* pairs, int E){
    int i = blockIdx.x * blockDim.x + threadIdx.x;
    if (i < E){
        int d = dst[i];
        int s = src[i];
        int pos = atomicAdd(&cursor[d], 1);
        pairs[pos] = make_int2(s, d);
    }
}

// Node linear via single fp16 MFMA (~1e-3 abs accuracy, sufficient).
// Y[r] = X[r] @ W + b (fp16 out). 128 rows/block (4 waves x 32 rows).
// Fused: blocks [0,g1): (X1,W1,b1)->Yb1; blocks [g1,..): (X2,W2,b2)->Yb2.
__global__ __launch_bounds__(256) void lin2_mfma(
        const float* X1, const unsigned short* W1, const float* b1,
        unsigned short* Yb1, int n1, int g1,
        const float* X2, const unsigned short* W2, const float* b2,
        unsigned short* Yb2, int n2){
    __shared__ unsigned short sB[16384];   // 32 KB
    const int tid = threadIdx.x;
    const int second = (blockIdx.x >= g1);
    const float* X = second ? X2 : X1;
    const unsigned short* W = second ? W2 : W1;
    const float* b = second ? b2 : b1;
    unsigned short* Yb = second ? Yb2 : Yb1;
    const int nrows = second ? n2 : n1;
    const int bidx = second ? (blockIdx.x - g1) : blockIdx.x;
    {
        const uint4* g = (const uint4*)W;
        uint4* l = (uint4*)sB;
        #pragma unroll
        for (int t = 0; t < 8; t++) l[tid + 256 * t] = g[tid + 256 * t];
    }
    const int wave = tid >> 6, lane = tid & 63;
    const int qd = lane >> 4, ln16 = lane & 15;
    const int row0 = bidx * 128 + wave * 32;
    int r0 = row0 + ln16;       if (r0 >= nrows) r0 = nrows - 1;
    int r1 = row0 + 16 + ln16;  if (r1 >= nrows) r1 = nrows - 1;
    f32x4 acc[2][8];
    #pragma unroll
    for (int rt = 0; rt < 2; rt++)
        #pragma unroll
        for (int nt = 0; nt < 8; nt++)
            acc[rt][nt] = (f32x4){0.f, 0.f, 0.f, 0.f};
    __syncthreads();
    #pragma unroll
    for (int kc = 0; kc < 4; kc++){
        const int koff = kc * 32 + qd * 8;
        half8 a[2];
        const float* px[2] = {X + (size_t)r0 * DD + koff, X + (size_t)r1 * DD + koff};
        #pragma unroll
        for (int rt = 0; rt < 2; rt++){
            float4 v0 = *(const float4*)(px[rt]);
            float4 v1 = *(const float4*)(px[rt] + 4);
            a[rt][0] = (_Float16)v0.x; a[rt][1] = (_Float16)v0.y;
            a[rt][2] = (_Float16)v0.z; a[rt][3] = (_Float16)v0.w;
            a[rt][4] = (_Float16)v1.x; a[rt][5] = (_Float16)v1.y;
            a[rt][6] = (_Float16)v1.z; a[rt][7] = (_Float16)v1.w;
        }
        #pragma unroll
        for (int nt = 0; nt < 8; nt++){
            const int fi = (((kc << 3) + nt) << 6 | lane) << 3;
            half8 bw = *(const half8*)&sB[fi];
            acc[0][nt] = __builtin_amdgcn_mfma_f32_16x16x32_f16(a[0], bw, acc[0][nt], 0, 0, 0);
            acc[1][nt] = __builtin_amdgcn_mfma_f32_16x16x32_f16(a[1], bw, acc[1][nt], 0, 0, 0);
        }
    }
    #pragma unroll
    for (int nt = 0; nt < 8; nt++){
        const int col = nt * 16 + ln16;
        const float bv = b[col];
        #pragma unroll
        for (int rt = 0; rt < 2; rt++){
            #pragma unroll
            for (int r = 0; r < 4; r++){
                int row = row0 + rt * 16 + qd * 4 + r;
                if (row < nrows){
                    float y = acc[rt][nt][r] + bv;
                    Yb[(size_t)row * DD + col] = h2u((_Float16)y);
                }
            }
        }
    }
}

// Final linear (fp32 in/out, in-place): Y = lrelu(X @ W + b)
__global__ __launch_bounds__(256) void lin_mfma(const float* X,
        const unsigned short* W, const float* b, float* Y, int nrows){
    __shared__ unsigned short sB[16384];
    const int tid = threadIdx.x;
    {
        const uint4* g = (const uint4*)W;
        uint4* l = (uint4*)sB;
        #pragma unroll
        for (int t = 0; t < 8; t++) l[tid + 256 * t] = g[tid + 256 * t];
    }
    const int wave = tid >> 6, lane = tid & 63;
    const int qd = lane >> 4, ln16 = lane & 15;
    const int row0 = blockIdx.x * 128 + wave * 32;
    int r0 = row0 + ln16;       if (r0 >= nrows) r0 = nrows - 1;
    int r1 = row0 + 16 + ln16;  if (r1 >= nrows) r1 = nrows - 1;
    f32x4 acc[2][8];
    #pragma unroll
    for (int rt = 0; rt < 2; rt++)
        #pragma unroll
        for (int nt = 0; nt < 8; nt++)
            acc[rt][nt] = (f32x4){0.f, 0.f, 0.f, 0.f};
    __syncthreads();
    #pragma unroll
    for (int kc = 0; kc < 4; kc++){
        const int koff = kc * 32 + qd * 8;
        half8 a[2];
        const float* px[2] = {X + (size_t)r0 * DD + koff, X + (size_t)r1 * DD + koff};
        #pragma unroll
        for (int rt = 0; rt < 2; rt++){
            float4 v0 = *(const float4*)(px[rt]);
            float4 v1 = *(const float4*)(px[rt] + 4);
            a[rt][0] = (_Float16)v0.x; a[rt][1] = (_Float16)v0.y;
            a[rt][2] = (_Float16)v0.z; a[rt][3] = (_Float16)v0.w;
            a[rt][4] = (_Float16)v1.x; a[rt][5] = (_Float16)v1.y;
            a[rt][6] = (_Float16)v1.z; a[rt][7] = (_Float16)v1.w;
        }
        #pragma unroll
        for (int nt = 0; nt < 8; nt++){
            const int fi = (((kc << 3) + nt) << 6 | lane) << 3;
            half8 bw = *(const half8*)&sB[fi];
            acc[0][nt] = __builtin_amdgcn_mfma_f32_16x16x32_f16(a[0], bw, acc[0][nt], 0, 0, 0);
            acc[1][nt] = __builtin_amdgcn_mfma_f32_16x16x32_f16(a[1], bw, acc[1][nt], 0, 0, 0);
        }
    }
    #pragma unroll
    for (int nt = 0; nt < 8; nt++){
        const int col = nt * 16 + ln16;
        const float bv = b[col];
        #pragma unroll
        for (int rt = 0; rt < 2; rt++){
            #pragma unroll
            for (int r = 0; r < 4; r++){
                int row = row0 + rt * 16 + qd * 4 + r;
                if (row < nrows){
                    float y = acc[rt][nt][r] + bv;
                    Y[(size_t)row * DD + col] = lrelu(y);
                }
            }
        }
    }
}

// A-fragment: 8 fp16 of lrelu(hs_row + hd_row) — packed fp16 math.
// lrelu(x) == max(x, 0.01*x), maps to v_pk_max_f16.
__device__ __forceinline__ half8 afrag_from(half8 a, half8 b){
    half8 s = a + b;
    return h8max(s, s * (_Float16)NEG);
}

// MFMA edge attention score on SORTED edges; 256 edges/block (8 waves).
// Best-measured structure (50.6us): rt-serialized, b_a1 folded into acc
// init, lrelu via v_max, __expf. exp() without +b2: per-node constant e^b2
// cancels exactly in alpha = ex/sum(ex).
__global__ __launch_bounds__(512) void edge_score_mfma(
        const unsigned short* hs_h, const unsigned short* hd_h,
        const int2* pairs,
        const unsigned short* wa1p, const float* ba1,
        const float* Wa2, const float* ba2,
        float* s_w, int E){
    __shared__ unsigned short sB[16384];  // 32 KB
    const int tid = threadIdx.x;
    {
        const uint4* g = (const uint4*)wa1p;
        uint4* l = (uint4*)sB;
        #pragma unroll
        for (int t = 0; t < 4; t++) l[tid + 512 * t] = g[tid + 512 * t];
    }
    const int wave = tid >> 6, lane = tid & 63;
    const int qd = lane >> 4, ln16 = lane & 15;
    const int e0 = blockIdx.x * 256 + wave * 32;
    float b1v[8], w2v[8];
    #pragma unroll
    for (int nt = 0; nt < 8; nt++){
        b1v[nt] = ba1[nt * 16 + ln16];
        w2v[nt] = Wa2[nt * 16 + ln16];
    }
    __syncthreads();
    for (int rt = 0; rt < 2; rt++){
        int eid = e0 + rt * 16 + ln16;
        if (eid >= E) eid = E - 1;
        const int2 pp = pairs[eid];
        f32x4 acc[8];
        #pragma unroll
        for (int nt = 0; nt < 8; nt++)
            acc[nt] = (f32x4){b1v[nt], b1v[nt], b1v[nt], b1v[nt]};
        #pragma unroll
        for (int kc = 0; kc < 4; kc++){
            const int koff = kc * 32 + qd * 8;
            half8 af = afrag_from(*(const half8*)(hs_h + (size_t)pp.x * DD + koff),
                                  *(const half8*)(hd_h + (size_t)pp.y * DD + koff));
            #pragma unroll
            for (int nt = 0; nt < 8; nt++){
                half8 bf = *(const half8*)&sB[(((kc << 3) + nt) << 6 | lane) << 3];
                acc[nt] = __builtin_amdgcn_mfma_f32_16x16x32_f16(af, bf, acc[nt], 0, 0, 0);
            }
        }
        float p[4] = {0.f, 0.f, 0.f, 0.f};
        #pragma unroll
        for (int nt = 0; nt < 8; nt++)
            #pragma unroll
            for (int r = 0; r < 4; r++){
                float z = acc[nt][r];
                z = fmaxf(z, NEG * z);      // lrelu via v_max_f32
                p[r] += z * w2v[nt];
            }
        #pragma unroll
        for (int r = 0; r < 4; r++){
            float v = p[r];
            #pragma unroll
            for (int off = 1; off < 16; off <<= 1) v += __shfl_xor(v, off, 64);
            p[r] = __expf(v);
        }
        if (ln16 == 0){
            int row = e0 + rt * 16 + qd * 4;
            #pragma unroll
            for (int r = 0; r < 4; r++)
                if (row + r < E) s_w[row + r] = p[r];
        }
    }
}

// one wave per dst node, 2 edges per pass (lanes 0-31: even edge, 32-63: odd).
// Each lane loads ushort4 (8 B) — full 256 B row per 32-lane half, coalesced.
// Main loop: 8 edges/iter, 4 gathers in flight (covers typical deg=12.8).
// Tail: 4 edges/pass, 2 clamped+masked gathers in flight.
// nf[n] = (sum_e w_e * hs[src_e]) / (sum_e w_e) + hd[n]
__global__ __launch_bounds__(256) void agg_softmax(const unsigned short* hs_h,
        const unsigned short* hd_h, const int* row_off, const int2* pairs,
        const float* s_w, float* nf, int n_dst){
    const int w = (blockIdx.x * blockDim.x + threadIdx.x) >> 6;
    const int lane = threadIdx.x & 63;
    if (w >= n_dst) return;
    const int beg = row_off[w], end = row_off[w + 1];
    const int hf = lane >> 5, l32 = lane & 31;
    float4 acc = make_float4(0.f, 0.f, 0.f, 0.f);
    float sa = 0.f;
    int e = beg;
    for (; e + 7 < end; e += 8){
        int rows[4]; float wv[4]; ushort4 uv[4];
        #pragma unroll
        for (int j = 0; j < 4; j++){
            int ee = e + 2 * j + hf;
            rows[j] = pairs[ee].x;
            wv[j] = s_w[ee];
        }
        #pragma unroll
        for (int j = 0; j < 4; j++)
            uv[j] = *(const ushort4*)(hs_h + (size_t)rows[j] * DD + l32 * 4);
        #pragma unroll
        for (int j = 0; j < 4; j++){
            acc.x += wv[j] * (float)u2h(uv[j].x);
            acc.y += wv[j] * (float)u2h(uv[j].y);
            acc.z += wv[j] * (float)u2h(uv[j].z);
            acc.w += wv[j] * (float)u2h(uv[j].w);
            sa += wv[j];
        }
    }
    for (; e < end; e += 4){
        // two edges per half-wave, clamped index + masked weight
        int ee0 = e + hf;          int ee1 = e + 2 + hf;
        int ec0 = ee0 < end ? ee0 : end - 1;
        int ec1 = ee1 < end ? ee1 : end - 1;
        int r0 = pairs[ec0].x, r1 = pairs[ec1].x;
        float wv0 = (ee0 < end) ? s_w[ec0] : 0.f;
        float wv1 = (ee1 < end) ? s_w[ec1] : 0.f;
        ushort4 u0 = *(const ushort4*)(hs_h + (size_t)r0 * DD + l32 * 4);
        ushort4 u1 = *(const ushort4*)(hs_h + (size_t)r1 * DD + l32 * 4);
        acc.x += wv0 * (float)u2h(u0.x) + wv1 * (float)u2h(u1.x);
        acc.y += wv0 * (float)u2h(u0.y) + wv1 * (float)u2h(u1.y);
        acc.z += wv0 * (float)u2h(u0.z) + wv1 * (float)u2h(u1.z);
        acc.w += wv0 * (float)u2h(u0.w) + wv1 * (float)u2h(u1.w);
        sa += wv0 + wv1;
    }
    // combine the two half-wave partials (same dims, disjoint edges)
    acc.x += __shfl_xor(acc.x, 32, 64);
    acc.y += __shfl_xor(acc.y, 32, 64);
    acc.z += __shfl_xor(acc.z, 32, 64);
    acc.w += __shfl_xor(acc.w, 32, 64);
    sa    += __shfl_xor(sa, 32, 64);
    const float inv = (end > beg) ? 1.f / sa : 0.f;
    if (hf == 0){
        ushort4 hu = *(const ushort4*)(hd_h + (size_t)w * DD + l32 * 4);
        const float gx = (end > beg) ? 1.f : 0.f;
        float4 out;
        out.x = acc.x * inv + gx * (float)u2h(hu.x);
        out.y = acc.y * inv + gx * (float)u2h(hu.y);
        out.z = acc.z * inv + gx * (float)u2h(hu.z);
        out.w = acc.w * inv + gx * (float)u2h(hu.w);
        *(float4*)(nf + (size_t)w * DD + l32 * 4) = out;
    }
}

extern "C" void kernel_launch(void* const* d_in, const int* in_sizes, int n_in,
                              void* d_out, int out_size, void* d_ws, size_t ws_size,
                              hipStream_t stream){
    const float* feat_src = (const float*)d_in[0];
    const float* feat_dst = (const float*)d_in[1];
    const int*   src_idx  = (const int*)d_in[2];
    const int*   dst_idx  = (const int*)d_in[3];
    const float* W_src = (const float*)d_in[4];
    const float* b_src = (const float*)d_in[5];
    const float* W_dst = (const float*)d_in[6];
    const float* b_dst = (const float*)d_in[7];
    const float* W_a1  = (const float*)d_in[8];
    const float* b_a1  = (const float*)d_in[9];
    const float* W_a2  = (const float*)d_in[10];
    const float* b_a2  = (const float*)d_in[11];
    const float* W_out = (const float*)d_in[12];
    const float* b_out = (const float*)d_in[13];
    const int n_src = in_sizes[0] / DD;
    const int n_dst = in_sizes[1] / DD;
    const int E = in_sizes[2];
    const int nchunks = (n_dst + SCHUNK - 1) / SCHUNK;

    // workspace layout (all 16B-aligned segments)
    char* p = (char*)d_ws;
    unsigned short* hs_h = (unsigned short*)p;  p += (size_t)n_src * DD * 2;
    unsigned short* hd_h = (unsigned short*)p;  p += (size_t)n_dst * DD * 2;
    unsigned short* wpack = (unsigned short*)p; p += 4 * 16384 * 2;
    float* s_w = (float*)p;                     p += (size_t)E * 4;
    int2* pairs = (int2*)p;                     p += (size_t)E * 8;
    int* deg = (int*)p;                         p += (size_t)n_dst * 4;
    int* cursor = (int*)p;                      p += (size_t)n_dst * 4;
    int* part = (int*)p;                        p += 64 * 4;
    int* row_off = (int*)p;                     p += ((size_t)n_dst + 1) * 4;
    float* nf = (float*)d_out;

    const unsigned short* wa1p = wpack;
    const unsigned short* wsrc = wpack + 1 * 16384;
    const unsigned short* wdst = wpack + 2 * 16384;
    const unsigned short* wout = wpack + 3 * 16384;

    hipMemsetAsync(deg, 0, (size_t)n_dst * 4, stream);
    const int nhist = (E + 255) / 256;
    const int npack = (4 * 16384 + 255) / 256;
    hist_pack<<<nhist + npack, 256, 0, stream>>>(dst_idx, deg, E, nhist,
                                                 W_a1, W_src, W_dst, W_out, wpack);
    scan1<<<nchunks, 1024, 0, stream>>>(deg, part, n_dst);
    scan2<<<nchunks, 1024, 0, stream>>>(deg, part, row_off, cursor, n_dst, nchunks);
    scatter_pairs<<<(E + 255) / 256, 256, 0, stream>>>(src_idx, dst_idx, cursor,
                                                       pairs, E);
    const int g1 = (n_src + 127) / 128;
    const int g2 = (n_dst + 127) / 128;
    lin2_mfma<<<g1 + g2, 256, 0, stream>>>(feat_src, wsrc, b_src, hs_h, n_src, g1,
                                           feat_dst, wdst, b_dst, hd_h, n_dst);
    edge_score_mfma<<<(E + 255) / 256, 512, 0, stream>>>(hs_h, hd_h, pairs, wa1p, b_a1,
                                                         W_a2, b_a2, s_w, E);
    agg_softmax<<<((size_t)n_dst * 64 + 255) / 256, 256, 0, stream>>>(hs_h, hd_h, row_off,
                                                                      pairs, s_w, nf, n_dst);
    lin_mfma<<<g2, 256, 0, stream>>>(nf, wout, b_out, nf, n_dst);
}

// Round 6
// 272.272 us; speedup vs baseline: 1.2054x; 1.0790x over previous
//
#include <hip/hip_runtime.h>
#include <math.h>

#define DD 128
#define NEG 0.01f
#define SCHUNK 4096

typedef __attribute__((ext_vector_type(8))) _Float16 half8;
typedef __attribute__((ext_vector_type(4))) float f32x4;

__device__ __forceinline__ float lrelu(float x){ return x > 0.f ? x : NEG * x; }

__device__ __forceinline__ unsigned short h2u(_Float16 h){
    union { _Float16 h; unsigned short u; } v; v.h = h; return v.u;
}
__device__ __forceinline__ _Float16 u2h(unsigned short u){
    union { unsigned short u; _Float16 h; } v; v.u = u; return v.h;
}

__device__ __forceinline__ half8 h8max(half8 x, half8 y){
#if __has_builtin(__builtin_elementwise_max)
    return __builtin_elementwise_max(x, y);
#else
    half8 r;
    #pragma unroll
    for (int i = 0; i < 8; i++) r[i] = x[i] > y[i] ? x[i] : y[i];
    return r;
#endif
}

// histogram (returning per-edge rank) + fp16 weight pack fused.
// rank[i] = this edge's arrival index within its dst bucket -> scatter needs
// no atomics. wpack segs: 0 Wa1, 1 Wsrc, 2 Wdst, 3 Wout (B-fragment order).
__global__ void hist_pack(const int* dst, int* deg, int* rank, int E, int nhist,
                          const float* Wa1, const float* Wsrc,
                          const float* Wdst, const float* Wout,
                          unsigned short* wpack){
    const int bid = blockIdx.x;
    if (bid < nhist){
        int i = bid * 256 + threadIdx.x;
        if (i < E) rank[i] = atomicAdd(&deg[dst[i]], 1);
    } else {
        int i = (bid - nhist) * 256 + threadIdx.x;   // [0, 4*16384)
        if (i >= 4 * 16384) return;
        int seg = i >> 14, t = i & 16383;
        int j = t & 7, lane = (t >> 3) & 63, nt = (t >> 9) & 7, kc = t >> 12;
        int k = kc * 32 + (lane >> 4) * 8 + j;
        int n = nt * 16 + (lane & 15);
        const float* W = (seg == 0) ? Wa1 : (seg == 1) ? Wsrc : (seg == 2) ? Wdst : Wout;
        wpack[i] = h2u((_Float16)W[k * DD + n]);
    }
}

// two-level scan, level 1: per-chunk sums (chunk = 4096 ints)
__global__ __launch_bounds__(1024) void scan1(const int* deg, int* part, int n){
    __shared__ int wsum[16];
    const int tid = threadIdx.x;
    const int lane = tid & 63, wid = tid >> 6;
    int i4 = blockIdx.x * SCHUNK + tid * 4;
    int4 v = make_int4(0, 0, 0, 0);
    if (i4 + 3 < n) v = *(const int4*)(deg + i4);
    else {
        if (i4 + 0 < n) v.x = deg[i4 + 0];
        if (i4 + 1 < n) v.y = deg[i4 + 1];
        if (i4 + 2 < n) v.z = deg[i4 + 2];
        if (i4 + 3 < n) v.w = deg[i4 + 3];
    }
    int t = v.x + v.y + v.z + v.w;
    #pragma unroll
    for (int off = 1; off < 64; off <<= 1) t += __shfl_xor(t, off, 64);
    if (lane == 0) wsum[wid] = t;
    __syncthreads();
    if (tid == 0){
        int s = 0;
        #pragma unroll
        for (int j = 0; j < 16; j++) s += wsum[j];
        part[blockIdx.x] = s;
    }
}

// two-level scan, level 2: exclusive offsets (row_off only; no cursor needed)
__global__ __launch_bounds__(1024) void scan2(const int* deg, const int* part,
        int* row_off, int n, int nchunks){
    __shared__ int wsum[16];
    const int tid = threadIdx.x;
    const int lane = tid & 63, wid = tid >> 6;
    const int b = blockIdx.x;
    int carry = 0;
    for (int j = 0; j < b; j++) carry += part[j];
    int i4 = b * SCHUNK + tid * 4;
    int4 v = make_int4(0, 0, 0, 0);
    if (i4 + 3 < n) v = *(const int4*)(deg + i4);
    else {
        if (i4 + 0 < n) v.x = deg[i4 + 0];
        if (i4 + 1 < n) v.y = deg[i4 + 1];
        if (i4 + 2 < n) v.z = deg[i4 + 2];
        if (i4 + 3 < n) v.w = deg[i4 + 3];
    }
    int tsum = v.x + v.y + v.z + v.w;
    int x = tsum;
    #pragma unroll
    for (int off = 1; off < 64; off <<= 1){
        int t = __shfl_up(x, off, 64);
        if (lane >= off) x += t;
    }
    if (lane == 63) wsum[wid] = x;
    __syncthreads();
    int wprefix = 0;
    #pragma unroll
    for (int j = 0; j < 16; j++) if (j < wid) wprefix += wsum[j];
    int excl = carry + wprefix + (x - tsum);
    if (i4 + 3 < n){
        int4 o;
        o.x = excl; o.y = excl + v.x; o.z = o.y + v.y; o.w = o.z + v.z;
        *(int4*)(row_off + i4) = o;
    } else {
        int a = excl;
        if (i4 + 0 < n){ row_off[i4 + 0] = a; a += v.x; }
        if (i4 + 1 < n){ row_off[i4 + 1] = a; a += v.y; }
        if (i4 + 2 < n){ row_off[i4 + 2] = a; a += v.z; }
        if (i4 + 3 < n){ row_off[i4 + 3] = a; }
    }
    if (b == 0 && tid == 0){
        int tot = 0;
        for (int j = 0; j < nchunks; j++) tot += part[j];
        row_off[n] = tot;
    }
}

// Fused: blocks [0,nsc): atomic-free scatter (pairs[row_off[d]+rank[i]]);
// blocks [nsc,..): node linear via fp16 MFMA (two inputs, disjoint ranges).
// Y[r] = X[r] @ W + b (fp16 out). 128 rows/block (4 waves x 32 rows).
__global__ __launch_bounds__(256) void scatter_lin2(
        const int* src, const int* dst, const int* row_off, const int* rank,
        int2* pairs, int E, int nsc,
        const float* X1, const unsigned short* W1, const float* b1,
        unsigned short* Yb1, int n1, int g1,
        const float* X2, const unsigned short* W2, const float* b2,
        unsigned short* Yb2, int n2){
    __shared__ unsigned short sB[16384];   // 32 KB (lin2 blocks only)
    const int tid = threadIdx.x;
    if (blockIdx.x < nsc){
        int i = blockIdx.x * 256 + tid;
        if (i < E){
            int d = dst[i];
            pairs[row_off[d] + rank[i]] = make_int2(src[i], d);
        }
        return;
    }
    const int lb = blockIdx.x - nsc;
    const int second = (lb >= g1);
    const float* X = second ? X2 : X1;
    const unsigned short* W = second ? W2 : W1;
    const float* b = second ? b2 : b1;
    unsigned short* Yb = second ? Yb2 : Yb1;
    const int nrows = second ? n2 : n1;
    const int bidx = second ? (lb - g1) : lb;
    {
        const uint4* g = (const uint4*)W;
        uint4* l = (uint4*)sB;
        #pragma unroll
        for (int t = 0; t < 8; t++) l[tid + 256 * t] = g[tid + 256 * t];
    }
    const int wave = tid >> 6, lane = tid & 63;
    const int qd = lane >> 4, ln16 = lane & 15;
    const int row0 = bidx * 128 + wave * 32;
    int r0 = row0 + ln16;       if (r0 >= nrows) r0 = nrows - 1;
    int r1 = row0 + 16 + ln16;  if (r1 >= nrows) r1 = nrows - 1;
    f32x4 acc[2][8];
    #pragma unroll
    for (int rt = 0; rt < 2; rt++)
        #pragma unroll
        for (int nt = 0; nt < 8; nt++)
            acc[rt][nt] = (f32x4){0.f, 0.f, 0.f, 0.f};
    __syncthreads();
    #pragma unroll
    for (int kc = 0; kc < 4; kc++){
        const int koff = kc * 32 + qd * 8;
        half8 a[2];
        const float* px[2] = {X + (size_t)r0 * DD + koff, X + (size_t)r1 * DD + koff};
        #pragma unroll
        for (int rt = 0; rt < 2; rt++){
            float4 v0 = *(const float4*)(px[rt]);
            float4 v1 = *(const float4*)(px[rt] + 4);
            a[rt][0] = (_Float16)v0.x; a[rt][1] = (_Float16)v0.y;
            a[rt][2] = (_Float16)v0.z; a[rt][3] = (_Float16)v0.w;
            a[rt][4] = (_Float16)v1.x; a[rt][5] = (_Float16)v1.y;
            a[rt][6] = (_Float16)v1.z; a[rt][7] = (_Float16)v1.w;
        }
        #pragma unroll
        for (int nt = 0; nt < 8; nt++){
            const int fi = (((kc << 3) + nt) << 6 | lane) << 3;
            half8 bw = *(const half8*)&sB[fi];
            acc[0][nt] = __builtin_amdgcn_mfma_f32_16x16x32_f16(a[0], bw, acc[0][nt], 0, 0, 0);
            acc[1][nt] = __builtin_amdgcn_mfma_f32_16x16x32_f16(a[1], bw, acc[1][nt], 0, 0, 0);
        }
    }
    #pragma unroll
    for (int nt = 0; nt < 8; nt++){
        const int col = nt * 16 + ln16;
        const float bv = b[col];
        #pragma unroll
        for (int rt = 0; rt < 2; rt++){
            #pragma unroll
            for (int r = 0; r < 4; r++){
                int row = row0 + rt * 16 + qd * 4 + r;
                if (row < nrows){
                    float y = acc[rt][nt][r] + bv;
                    Yb[(size_t)row * DD + col] = h2u((_Float16)y);
                }
            }
        }
    }
}

// Final linear (fp32 in/out, in-place): Y = lrelu(X @ W + b)
__global__ __launch_bounds__(256) void lin_mfma(const float* X,
        const unsigned short* W, const float* b, float* Y, int nrows){
    __shared__ unsigned short sB[16384];
    const int tid = threadIdx.x;
    {
        const uint4* g = (const uint4*)W;
        uint4* l = (uint4*)sB;
        #pragma unroll
        for (int t = 0; t < 8; t++) l[tid + 256 * t] = g[tid + 256 * t];
    }
    const int wave = tid >> 6, lane = tid & 63;
    const int qd = lane >> 4, ln16 = lane & 15;
    const int row0 = blockIdx.x * 128 + wave * 32;
    int r0 = row0 + ln16;       if (r0 >= nrows) r0 = nrows - 1;
    int r1 = row0 + 16 + ln16;  if (r1 >= nrows) r1 = nrows - 1;
    f32x4 acc[2][8];
    #pragma unroll
    for (int rt = 0; rt < 2; rt++)
        #pragma unroll
        for (int nt = 0; nt < 8; nt++)
            acc[rt][nt] = (f32x4){0.f, 0.f, 0.f, 0.f};
    __syncthreads();
    #pragma unroll
    for (int kc = 0; kc < 4; kc++){
        const int koff = kc * 32 + qd * 8;
        half8 a[2];
        const float* px[2] = {X + (size_t)r0 * DD + koff, X + (size_t)r1 * DD + koff};
        #pragma unroll
        for (int rt = 0; rt < 2; rt++){
            float4 v0 = *(const float4*)(px[rt]);
            float4 v1 = *(const float4*)(px[rt] + 4);
            a[rt][0] = (_Float16)v0.x; a[rt][1] = (_Float16)v0.y;
            a[rt][2] = (_Float16)v0.z; a[rt][3] = (_Float16)v0.w;
            a[rt][4] = (_Float16)v1.x; a[rt][5] = (_Float16)v1.y;
            a[rt][6] = (_Float16)v1.z; a[rt][7] = (_Float16)v1.w;
        }
        #pragma unroll
        for (int nt = 0; nt < 8; nt++){
            const int fi = (((kc << 3) + nt) << 6 | lane) << 3;
            half8 bw = *(const half8*)&sB[fi];
            acc[0][nt] = __builtin_amdgcn_mfma_f32_16x16x32_f16(a[0], bw, acc[0][nt], 0, 0, 0);
            acc[1][nt] = __builtin_amdgcn_mfma_f32_16x16x32_f16(a[1], bw, acc[1][nt], 0, 0, 0);
        }
    }
    #pragma unroll
    for (int nt = 0; nt < 8; nt++){
        const int col = nt * 16 + ln16;
        const float bv = b[col];
        #pragma unroll
        for (int rt = 0; rt < 2; rt++){
            #pragma unroll
            for (int r = 0; r < 4; r++){
                int row = row0 + rt * 16 + qd * 4 + r;
                if (row < nrows){
                    float y = acc[rt][nt][r] + bv;
                    Y[(size_t)row * DD + col] = lrelu(y);
                }
            }
        }
    }
}

// A-fragment: 8 fp16 of lrelu(hs_row + hd_row) — packed fp16 math.
// lrelu(x) == max(x, 0.01*x), maps to v_pk_max_f16.
__device__ __forceinline__ half8 afrag_from(half8 a, half8 b){
    half8 s = a + b;
    return h8max(s, s * (_Float16)NEG);
}

// MFMA edge attention score on SORTED edges; 256 edges/block (8 waves).
// Best-measured structure (50.6us): rt-serialized, b_a1 folded into acc
// init, lrelu via v_max, __expf. exp() without +b2: per-node constant e^b2
// cancels exactly in alpha = ex/sum(ex).
__global__ __launch_bounds__(512) void edge_score_mfma(
        const unsigned short* hs_h, const unsigned short* hd_h,
        const int2* pairs,
        const unsigned short* wa1p, const float* ba1,
        const float* Wa2, const float* ba2,
        float* s_w, int E){
    __shared__ unsigned short sB[16384];  // 32 KB
    const int tid = threadIdx.x;
    {
        const uint4* g = (const uint4*)wa1p;
        uint4* l = (uint4*)sB;
        #pragma unroll
        for (int t = 0; t < 4; t++) l[tid + 512 * t] = g[tid + 512 * t];
    }
    const int wave = tid >> 6, lane = tid & 63;
    const int qd = lane >> 4, ln16 = lane & 15;
    const int e0 = blockIdx.x * 256 + wave * 32;
    float b1v[8], w2v[8];
    #pragma unroll
    for (int nt = 0; nt < 8; nt++){
        b1v[nt] = ba1[nt * 16 + ln16];
        w2v[nt] = Wa2[nt * 16 + ln16];
    }
    __syncthreads();
    for (int rt = 0; rt < 2; rt++){
        int eid = e0 + rt * 16 + ln16;
        if (eid >= E) eid = E - 1;
        const int2 pp = pairs[eid];
        f32x4 acc[8];
        #pragma unroll
        for (int nt = 0; nt < 8; nt++)
            acc[nt] = (f32x4){b1v[nt], b1v[nt], b1v[nt], b1v[nt]};
        #pragma unroll
        for (int kc = 0; kc < 4; kc++){
            const int koff = kc * 32 + qd * 8;
            half8 af = afrag_from(*(const half8*)(hs_h + (size_t)pp.x * DD + koff),
                                  *(const half8*)(hd_h + (size_t)pp.y * DD + koff));
            #pragma unroll
            for (int nt = 0; nt < 8; nt++){
                half8 bf = *(const half8*)&sB[(((kc << 3) + nt) << 6 | lane) << 3];
                acc[nt] = __builtin_amdgcn_mfma_f32_16x16x32_f16(af, bf, acc[nt], 0, 0, 0);
            }
        }
        float p[4] = {0.f, 0.f, 0.f, 0.f};
        #pragma unroll
        for (int nt = 0; nt < 8; nt++)
            #pragma unroll
            for (int r = 0; r < 4; r++){
                float z = acc[nt][r];
                z = fmaxf(z, NEG * z);      // lrelu via v_max_f32
                p[r] += z * w2v[nt];
            }
        #pragma unroll
        for (int r = 0; r < 4; r++){
            float v = p[r];
            #pragma unroll
            for (int off = 1; off < 16; off <<= 1) v += __shfl_xor(v, off, 64);
            p[r] = __expf(v);
        }
        if (ln16 == 0){
            int row = e0 + rt * 16 + qd * 4;
            #pragma unroll
            for (int r = 0; r < 4; r++)
                if (row + r < E) s_w[row + r] = p[r];
        }
    }
}

// one wave per dst node, 2 edges per pass (lanes 0-31: even edge, 32-63: odd).
// Each lane loads ushort4 (8 B) — full 256 B row per 32-lane half, coalesced.
// Main loop: 8 edges/iter, 4 gathers in flight (covers typical deg=12.8).
// Tail: 4 edges/pass, 2 clamped+masked gathers in flight.
// nf[n] = (sum_e w_e * hs[src_e]) / (sum_e w_e) + hd[n]
__global__ __launch_bounds__(256) void agg_softmax(const unsigned short* hs_h,
        const unsigned short* hd_h, const int* row_off, const int2* pairs,
        const float* s_w, float* nf, int n_dst){
    const int w = (blockIdx.x * blockDim.x + threadIdx.x) >> 6;
    const int lane = threadIdx.x & 63;
    if (w >= n_dst) return;
    const int beg = row_off[w], end = row_off[w + 1];
    const int hf = lane >> 5, l32 = lane & 31;
    float4 acc = make_float4(0.f, 0.f, 0.f, 0.f);
    float sa = 0.f;
    int e = beg;
    for (; e + 7 < end; e += 8){
        int rows[4]; float wv[4]; ushort4 uv[4];
        #pragma unroll
        for (int j = 0; j < 4; j++){
            int ee = e + 2 * j + hf;
            rows[j] = pairs[ee].x;
            wv[j] = s_w[ee];
        }
        #pragma unroll
        for (int j = 0; j < 4; j++)
            uv[j] = *(const ushort4*)(hs_h + (size_t)rows[j] * DD + l32 * 4);
        #pragma unroll
        for (int j = 0; j < 4; j++){
            acc.x += wv[j] * (float)u2h(uv[j].x);
            acc.y += wv[j] * (float)u2h(uv[j].y);
            acc.z += wv[j] * (float)u2h(uv[j].z);
            acc.w += wv[j] * (float)u2h(uv[j].w);
            sa += wv[j];
        }
    }
    for (; e < end; e += 4){
        // two edges per half-wave, clamped index + masked weight
        int ee0 = e + hf;          int ee1 = e + 2 + hf;
        int ec0 = ee0 < end ? ee0 : end - 1;
        int ec1 = ee1 < end ? ee1 : end - 1;
        int r0 = pairs[ec0].x, r1 = pairs[ec1].x;
        float wv0 = (ee0 < end) ? s_w[ec0] : 0.f;
        float wv1 = (ee1 < end) ? s_w[ec1] : 0.f;
        ushort4 u0 = *(const ushort4*)(hs_h + (size_t)r0 * DD + l32 * 4);
        ushort4 u1 = *(const ushort4*)(hs_h + (size_t)r1 * DD + l32 * 4);
        acc.x += wv0 * (float)u2h(u0.x) + wv1 * (float)u2h(u1.x);
        acc.y += wv0 * (float)u2h(u0.y) + wv1 * (float)u2h(u1.y);
        acc.z += wv0 * (float)u2h(u0.z) + wv1 * (float)u2h(u1.z);
        acc.w += wv0 * (float)u2h(u0.w) + wv1 * (float)u2h(u1.w);
        sa += wv0 + wv1;
    }
    // combine the two half-wave partials (same dims, disjoint edges)
    acc.x += __shfl_xor(acc.x, 32, 64);
    acc.y += __shfl_xor(acc.y, 32, 64);
    acc.z += __shfl_xor(acc.z, 32, 64);
    acc.w += __shfl_xor(acc.w, 32, 64);
    sa    += __shfl_xor(sa, 32, 64);
    const float inv = (end > beg) ? 1.f / sa : 0.f;
    if (hf == 0){
        ushort4 hu = *(const ushort4*)(hd_h + (size_t)w * DD + l32 * 4);
        const float gx = (end > beg) ? 1.f : 0.f;
        float4 out;
        out.x = acc.x * inv + gx * (float)u2h(hu.x);
        out.y = acc.y * inv + gx * (float)u2h(hu.y);
        out.z = acc.z * inv + gx * (float)u2h(hu.z);
        out.w = acc.w * inv + gx * (float)u2h(hu.w);
        *(float4*)(nf + (size_t)w * DD + l32 * 4) = out;
    }
}

extern "C" void kernel_launch(void* const* d_in, const int* in_sizes, int n_in,
                              void* d_out, int out_size, void* d_ws, size_t ws_size,
                              hipStream_t stream){
    const float* feat_src = (const float*)d_in[0];
    const float* feat_dst = (const float*)d_in[1];
    const int*   src_idx  = (const int*)d_in[2];
    const int*   dst_idx  = (const int*)d_in[3];
    const float* W_src = (const float*)d_in[4];
    const float* b_src = (const float*)d_in[5];
    const float* W_dst = (const float*)d_in[6];
    const float* b_dst = (const float*)d_in[7];
    const float* W_a1  = (const float*)d_in[8];
    const float* b_a1  = (const float*)d_in[9];
    const float* W_a2  = (const float*)d_in[10];
    const float* b_a2  = (const float*)d_in[11];
    const float* W_out = (const float*)d_in[12];
    const float* b_out = (const float*)d_in[13];
    const int n_src = in_sizes[0] / DD;
    const int n_dst = in_sizes[1] / DD;
    const int E = in_sizes[2];
    const int nchunks = (n_dst + SCHUNK - 1) / SCHUNK;

    // workspace layout (all 16B-aligned segments)
    char* p = (char*)d_ws;
    unsigned short* hs_h = (unsigned short*)p;  p += (size_t)n_src * DD * 2;
    unsigned short* hd_h = (unsigned short*)p;  p += (size_t)n_dst * DD * 2;
    unsigned short* wpack = (unsigned short*)p; p += 4 * 16384 * 2;
    float* s_w = (float*)p;                     p += (size_t)E * 4;
    int2* pairs = (int2*)p;                     p += (size_t)E * 8;
    int* rank = (int*)p;                        p += (size_t)E * 4;
    int* deg = (int*)p;                         p += (size_t)n_dst * 4;
    int* part = (int*)p;                        p += 64 * 4;
    int* row_off = (int*)p;                     p += ((size_t)n_dst + 1) * 4;
    float* nf = (float*)d_out;

    const unsigned short* wa1p = wpack;
    const unsigned short* wsrc = wpack + 1 * 16384;
    const unsigned short* wdst = wpack + 2 * 16384;
    const unsigned short* wout = wpack + 3 * 16384;

    hipMemsetAsync(deg, 0, (size_t)n_dst * 4, stream);
    const int nhist = (E + 255) / 256;
    const int npack = (4 * 16384 + 255) / 256;
    hist_pack<<<nhist + npack, 256, 0, stream>>>(dst_idx, deg, rank, E, nhist,
                                                 W_a1, W_src, W_dst, W_out, wpack);
    scan1<<<nchunks, 1024, 0, stream>>>(deg, part, n_dst);
    scan2<<<nchunks, 1024, 0, stream>>>(deg, part, row_off, n_dst, nchunks);
    const int nsc = (E + 255) / 256;
    const int g1 = (n_src + 127) / 128;
    const int g2 = (n_dst + 127) / 128;
    scatter_lin2<<<nsc + g1 + g2, 256, 0, stream>>>(src_idx, dst_idx, row_off, rank,
                                                    pairs, E, nsc,
                                                    feat_src, wsrc, b_src, hs_h, n_src, g1,
                                                    feat_dst, wdst, b_dst, hd_h, n_dst);
    edge_score_mfma<<<(E + 255) / 256, 512, 0, stream>>>(hs_h, hd_h, pairs, wa1p, b_a1,
                                                         W_a2, b_a2, s_w, E);
    agg_softmax<<<((size_t)n_dst * 64 + 255) / 256, 256, 0, stream>>>(hs_h, hd_h, row_off,
                                                                      pairs, s_w, nf, n_dst);
    lin_mfma<<<g2, 256, 0, stream>>>(nf, wout, b_out, nf, n_dst);
}